// Round 5
// baseline (31.642 us; speedup 1.0000x reference)
//
#include <hip/hip_runtime.h>

// GrowingSignature: truncated iterated-sums signature, levels 1..4, F=4.
// x: (32, 512, 4) f32;  out: (32, 512, 341) f32.
// 2-kernel chunked scan with Chen combine; all serial loops 1-deep
// software-pipelined (prefetch next iter's LDS reads into registers).
// Word layout (signatory order): len1 cols 1..4, len2 cols 5..20,
// len3 cols 21..84, len4 cols 85..340; word (a,b,c,e) -> 85+64a+16b+4c+e.

#define SIG_B 32
#define SIG_L 512
#define SIG_NSTEP 511
#define SIG_ROW 341
#define SIG_CS 32            // chunk size (increments)
#define SIG_C 16             // chunks per batch
#define SIG_PAD 344          // padded row stride in workspace (floats, %4==0)

__device__ __forceinline__ float sel4(const float4 v, const int i) {
    // runtime component select -> v_cndmask chain (no scratch, no LDS)
    return i == 0 ? v.x : (i == 1 ? v.y : (i == 2 ? v.z : v.w));
}

// ---------- Kernel A: local chunk signatures ----------
__global__ __launch_bounds__(256) void sigA(const float* __restrict__ x,
                                            float* __restrict__ Lsig) {
    const int bc = blockIdx.x;
    const int b = bc / SIG_C, c = bc % SIG_C;
    const int tid = threadIdx.x;
    const int t0 = c * SIG_CS;
    const int nt = min(SIG_CS, SIG_NSTEP - t0);   // 32, or 31 for last chunk

    __shared__ float dlds[SIG_CS * 4];
    const float* xb = x + ((size_t)b * SIG_L + t0) * 4;
    if (tid < nt) {
        float4 x0 = *(const float4*)(xb + tid * 4);
        float4 x1 = *(const float4*)(xb + (tid + 1) * 4);
        *(float4*)(dlds + tid * 4) =
            make_float4(x1.x - x0.x, x1.y - x0.y, x1.z - x0.z, x1.w - x0.w);
    }
    __syncthreads();

    const int a = tid >> 6, bb = (tid >> 4) & 3, cc = (tid >> 2) & 3, ee = tid & 3;
    float s1 = 0.f, s2 = 0.f, s3 = 0.f, s4 = 0.f;

    const float4* dv4 = (const float4*)dlds;
    float4 dv = dv4[0];                           // broadcast read (same addr)
    for (int t = 0; t < nt; ++t) {
        const int tn = (t + 1 < nt) ? t + 1 : t;
        const float4 dn = dv4[tn];                // prefetch next iteration
        const float da = sel4(dv, a), db = sel4(dv, bb),
                    dc = sel4(dv, cc), de = sel4(dv, ee);
        s4 = fmaf(s3, de, s4);  // top level first: consumes pre-update s3
        s3 = fmaf(s2, dc, s3);
        s2 = fmaf(s1, db, s2);
        s1 += da;
        dv = dn;
    }
    float* Lr = Lsig + (size_t)bc * SIG_PAD;
    if ((tid & 63) == 0) Lr[1 + a] = s1;
    if ((tid & 15) == 0) Lr[5 + (tid >> 4)] = s2;
    if ((tid & 3) == 0)  Lr[21 + (tid >> 2)] = s3;
    Lr[85 + tid] = s4;
}

// load the 10 combine inputs of chunk-signature row j into named registers
#define SIG_LOADL(j, A, Bv, Cv, E, AB, BC, CE, ABC, BCE, L4) do {      \
        const float* Lc_ = L + (j) * SIG_PAD;                          \
        A   = Lc_[1 + a];  Bv  = Lc_[1 + bb];                          \
        Cv  = Lc_[1 + cc]; E   = Lc_[1 + ee];                          \
        AB  = Lc_[5 + 4 * a + bb];  BC = Lc_[5 + 4 * bb + cc];         \
        CE  = Lc_[5 + 4 * cc + ee];                                    \
        ABC = Lc_[21 + 16 * a + 4 * bb + cc];                          \
        BCE = Lc_[21 + 16 * bb + 4 * cc + ee];                         \
        L4  = Lc_[85 + tid];                                           \
    } while (0)

// ---------- Kernel C: per-block prefix combine + output scan ----------
__global__ __launch_bounds__(256) void sigC(const float* __restrict__ x,
                                            const float* __restrict__ Lsig,
                                            float* __restrict__ out) {
    const int bc = blockIdx.x;
    const int b = bc / SIG_C, c = bc % SIG_C;
    const int tid = threadIdx.x;
    const int t0 = c * SIG_CS;
    const int nt = min(SIG_CS, SIG_NSTEP - t0);

    __shared__ float dlds[SIG_CS * 4];
    __shared__ float L[SIG_C * SIG_PAD];

    const float* xb = x + ((size_t)b * SIG_L + t0) * 4;
    if (tid < nt) {
        float4 x0 = *(const float4*)(xb + tid * 4);
        float4 x1 = *(const float4*)(xb + (tid + 1) * 4);
        *(float4*)(dlds + tid * 4) =
            make_float4(x1.x - x0.x, x1.y - x0.y, x1.z - x0.z, x1.w - x0.w);
    }
    // Stage the c preceding chunk signatures (only what this block combines).
    {
        const float4* Lb4 = (const float4*)(Lsig + (size_t)b * SIG_C * SIG_PAD);
        float4* L4p = (float4*)L;
        const int n4 = c * (SIG_PAD / 4);
        for (int i = tid; i < n4; i += 256) L4p[i] = Lb4[i];
    }
    __syncthreads();

    const int a = tid >> 6, bb = (tid >> 4) & 3, cc = (tid >> 2) & 3, ee = tid & 3;

    // Chen-combine chunks 0..c-1 -> prefix (p1..p4), 1-deep pipelined.
    float p1 = 0.f, p2 = 0.f, p3 = 0.f, p4 = 0.f;
    if (c > 0) {
        float A0, B0, C0, E0, AB0, BC0, CE0, ABC0, BCE0, L40;
        SIG_LOADL(0, A0, B0, C0, E0, AB0, BC0, CE0, ABC0, BCE0, L40);
        for (int j = 0; j < c; ++j) {
            float A1, B1, C1, E1, AB1, BC1, CE1, ABC1, BCE1, L41;
            const int jn = (j + 1 < c) ? j + 1 : j;
            SIG_LOADL(jn, A1, B1, C1, E1, AB1, BC1, CE1, ABC1, BCE1, L41);
            p4 += p3 * E0 + p2 * CE0 + p1 * BCE0 + L40;  // pre-update p1..p3
            p3 += p2 * C0 + p1 * BC0 + ABC0;
            p2 += p1 * B0 + AB0;
            p1 += A0;
            A0 = A1; B0 = B1; C0 = C1; E0 = E1; AB0 = AB1;
            BC0 = BC1; CE0 = CE1; ABC0 = ABC1; BCE0 = BCE1; L40 = L41;
        }
    }

    // local suffix chains: (a,b,c,e)=s*, (b,c,e)=x*, (c,e)=v*, (e)=u1
    float s1 = 0.f, s2 = 0.f, s3 = 0.f, s4 = 0.f;
    float x1_ = 0.f, x2_ = 0.f, x3_ = 0.f;
    float v1 = 0.f, v2 = 0.f;
    float u1 = 0.f;

    float* row = out + ((size_t)b * SIG_L + (t0 + 1)) * SIG_ROW;

    if (c == 0) {  // row 0: [1, zeros]
        float* r0 = out + (size_t)b * SIG_L * SIG_ROW;
        if (tid == 0)        __builtin_nontemporal_store(1.0f, r0 + 0);
        if ((tid & 63) == 0) __builtin_nontemporal_store(0.f, r0 + 1 + a);
        if ((tid & 15) == 0) __builtin_nontemporal_store(0.f, r0 + 5 + (tid >> 4));
        if ((tid & 3) == 0)  __builtin_nontemporal_store(0.f, r0 + 21 + (tid >> 2));
        __builtin_nontemporal_store(0.f, r0 + 85 + tid);
    }

    const float4* dv4 = (const float4*)dlds;
    float4 dv = dv4[0];
    for (int t = 0; t < nt; ++t) {
        const int tn = (t + 1 < nt) ? t + 1 : t;
        const float4 dn = dv4[tn];                // prefetch next iteration
        const float da = sel4(dv, a), db = sel4(dv, bb),
                    dc = sel4(dv, cc), de = sel4(dv, ee);
        // update all suffix chains, top level first (pre-update lower levels)
        s4 = fmaf(s3, de, s4); s3 = fmaf(s2, dc, s3); s2 = fmaf(s1, db, s2); s1 += da;
        x3_ = fmaf(x2_, de, x3_); x2_ = fmaf(x1_, dc, x2_); x1_ += db;
        v2 = fmaf(v1, de, v2); v1 += dc;
        u1 += de;

        if (tid == 0)        __builtin_nontemporal_store(1.0f, row + 0);
        if ((tid & 63) == 0) __builtin_nontemporal_store(p1 + s1, row + 1 + a);
        if ((tid & 15) == 0) __builtin_nontemporal_store(p2 + p1 * x1_ + s2,
                                                         row + 5 + (tid >> 4));
        if ((tid & 3) == 0)  __builtin_nontemporal_store(p3 + p2 * v1 + p1 * x2_ + s3,
                                                         row + 21 + (tid >> 2));
        __builtin_nontemporal_store(p4 + p3 * u1 + p2 * v2 + p1 * x3_ + s4,
                                    row + 85 + tid);  // coalesced
        row += SIG_ROW;
        dv = dn;
    }
}

extern "C" void kernel_launch(void* const* d_in, const int* in_sizes, int n_in,
                              void* d_out, int out_size, void* d_ws, size_t ws_size,
                              hipStream_t stream) {
    const float* x = (const float*)d_in[0];   // (32, 512, 4) f32
    float* out = (float*)d_out;               // (32, 512, 341) f32
    float* Lsig = (float*)d_ws;               // 512 * 344 floats

    sigA<<<SIG_B * SIG_C, 256, 0, stream>>>(x, Lsig);
    sigC<<<SIG_B * SIG_C, 256, 0, stream>>>(x, Lsig, out);
}

// Round 6
// 29.205 us; speedup vs baseline: 1.0834x; 1.0834x over previous
//
#include <hip/hip_runtime.h>

// GrowingSignature: truncated iterated-sums signature, levels 1..4, F=4.
// x: (32, 512, 4) f32;  out: (32, 512, 341) f32.
// 2-kernel chunked scan with Chen combine. CS=16/C=32 minimizes the serial
// critical path (2*CS + C); scan loops are constant-trip (16) with
// zero-padded increments so the compiler fully unrolls and prefetches.
// Word layout (signatory order): len1 cols 1..4, len2 cols 5..20,
// len3 cols 21..84, len4 cols 85..340; word (a,b,c,e) -> 85+64a+16b+4c+e.

#define SIG_B 32
#define SIG_L 512
#define SIG_NSTEP 511
#define SIG_ROW 341
#define SIG_CS 16            // chunk size (increments)
#define SIG_C 32             // chunks per batch
#define SIG_PAD 344          // padded row stride in workspace (floats, %4==0)

// ---------- Kernel A: local chunk signatures ----------
__global__ __launch_bounds__(256) void sigA(const float* __restrict__ x,
                                            float* __restrict__ Lsig) {
    const int bc = blockIdx.x;
    const int b = bc / SIG_C, c = bc % SIG_C;
    const int tid = threadIdx.x;
    const int t0 = c * SIG_CS;
    const int nt = min(SIG_CS, SIG_NSTEP - t0);   // 16, or 15 for last chunk

    __shared__ float dlds[SIG_CS * 4];
    const float* xb = x + ((size_t)b * SIG_L + t0) * 4;
    if (tid < SIG_CS) {
        float4 d = make_float4(0.f, 0.f, 0.f, 0.f);
        if (tid < nt) {
            float4 x0 = *(const float4*)(xb + tid * 4);
            float4 x1 = *(const float4*)(xb + (tid + 1) * 4);
            d = make_float4(x1.x - x0.x, x1.y - x0.y, x1.z - x0.z, x1.w - x0.w);
        }
        *(float4*)(dlds + tid * 4) = d;           // zero-padded tail
    }
    __syncthreads();

    const int a = tid >> 6, bb = (tid >> 4) & 3, cc = (tid >> 2) & 3, ee = tid & 3;
    float s1 = 0.f, s2 = 0.f, s3 = 0.f, s4 = 0.f;

#pragma unroll
    for (int t = 0; t < SIG_CS; ++t) {            // constant trip -> full unroll
        const float* dp = dlds + t * 4;
        const float da = dp[a], db = dp[bb], dc = dp[cc], de = dp[ee];
        s4 = fmaf(s3, de, s4);  // top level first: consumes pre-update s3
        s3 = fmaf(s2, dc, s3);
        s2 = fmaf(s1, db, s2);
        s1 += da;
    }
    float* Lr = Lsig + (size_t)bc * SIG_PAD;
    if ((tid & 63) == 0) Lr[1 + a] = s1;
    if ((tid & 15) == 0) Lr[5 + (tid >> 4)] = s2;
    if ((tid & 3) == 0)  Lr[21 + (tid >> 2)] = s3;
    Lr[85 + tid] = s4;
}

// ---------- Kernel C: per-block prefix combine + output scan ----------
__global__ __launch_bounds__(256) void sigC(const float* __restrict__ x,
                                            const float* __restrict__ Lsig,
                                            float* __restrict__ out) {
    const int bc = blockIdx.x;
    const int b = bc / SIG_C, c = bc % SIG_C;
    const int tid = threadIdx.x;
    const int t0 = c * SIG_CS;
    const int nt = min(SIG_CS, SIG_NSTEP - t0);

    __shared__ float dlds[SIG_CS * 4];
    __shared__ float L[SIG_C * SIG_PAD];

    const float* xb = x + ((size_t)b * SIG_L + t0) * 4;
    if (tid < SIG_CS) {
        float4 d = make_float4(0.f, 0.f, 0.f, 0.f);
        if (tid < nt) {
            float4 x0 = *(const float4*)(xb + tid * 4);
            float4 x1 = *(const float4*)(xb + (tid + 1) * 4);
            d = make_float4(x1.x - x0.x, x1.y - x0.y, x1.z - x0.z, x1.w - x0.w);
        }
        *(float4*)(dlds + tid * 4) = d;           // zero-padded tail
    }
    // Stage the c preceding chunk signatures (only what this block combines).
    {
        const float4* Lb4 = (const float4*)(Lsig + (size_t)b * SIG_C * SIG_PAD);
        float4* L4p = (float4*)L;
        const int n4 = c * (SIG_PAD / 4);
        for (int i = tid; i < n4; i += 256) L4p[i] = Lb4[i];
    }
    __syncthreads();

    const int a = tid >> 6, bb = (tid >> 4) & 3, cc = (tid >> 2) & 3, ee = tid & 3;

    // Chen-combine chunks 0..c-1 -> prefix (p1..p4) for this lane's word.
    float p1 = 0.f, p2 = 0.f, p3 = 0.f, p4 = 0.f;
    for (int j = 0; j < c; ++j) {
        const float* Lc = L + j * SIG_PAD;
        const float l1a = Lc[1 + a], l1b = Lc[1 + bb], l1c = Lc[1 + cc], l1e = Lc[1 + ee];
        const float l2ab = Lc[5 + 4 * a + bb], l2bc = Lc[5 + 4 * bb + cc],
                    l2ce = Lc[5 + 4 * cc + ee];
        const float l3abc = Lc[21 + 16 * a + 4 * bb + cc],
                    l3bce = Lc[21 + 16 * bb + 4 * cc + ee];
        const float l4 = Lc[85 + tid];
        p4 += p3 * l1e + p2 * l2ce + p1 * l3bce + l4;  // uses pre-update p1..p3
        p3 += p2 * l1c + p1 * l2bc + l3abc;
        p2 += p1 * l1b + l2ab;
        p1 += l1a;
    }

    // local suffix chains: (a,b,c,e)=s*, (b,c,e)=x*, (c,e)=v*, (e)=u1
    float s1 = 0.f, s2 = 0.f, s3 = 0.f, s4 = 0.f;
    float x1_ = 0.f, x2_ = 0.f, x3_ = 0.f;
    float v1 = 0.f, v2 = 0.f;
    float u1 = 0.f;

    float* row = out + ((size_t)b * SIG_L + (t0 + 1)) * SIG_ROW;

    if (c == 0) {  // row 0: [1, zeros]
        float* r0 = out + (size_t)b * SIG_L * SIG_ROW;
        if (tid == 0)        __builtin_nontemporal_store(1.0f, r0 + 0);
        if ((tid & 63) == 0) __builtin_nontemporal_store(0.f, r0 + 1 + a);
        if ((tid & 15) == 0) __builtin_nontemporal_store(0.f, r0 + 5 + (tid >> 4));
        if ((tid & 3) == 0)  __builtin_nontemporal_store(0.f, r0 + 21 + (tid >> 2));
        __builtin_nontemporal_store(0.f, r0 + 85 + tid);
    }

#pragma unroll
    for (int t = 0; t < SIG_CS; ++t) {            // constant trip -> full unroll
        const float* dp = dlds + t * 4;
        const float da = dp[a], db = dp[bb], dc = dp[cc], de = dp[ee];
        // update all suffix chains, top level first (pre-update lower levels)
        s4 = fmaf(s3, de, s4); s3 = fmaf(s2, dc, s3); s2 = fmaf(s1, db, s2); s1 += da;
        x3_ = fmaf(x2_, de, x3_); x2_ = fmaf(x1_, dc, x2_); x1_ += db;
        v2 = fmaf(v1, de, v2); v1 += dc;
        u1 += de;

        if (t < nt) {  // uniform guard (last chunk only pads 1 step)
            float* r = row + (size_t)t * SIG_ROW;
            if (tid == 0)        __builtin_nontemporal_store(1.0f, r + 0);
            if ((tid & 63) == 0) __builtin_nontemporal_store(p1 + s1, r + 1 + a);
            if ((tid & 15) == 0) __builtin_nontemporal_store(p2 + p1 * x1_ + s2,
                                                             r + 5 + (tid >> 4));
            if ((tid & 3) == 0)  __builtin_nontemporal_store(p3 + p2 * v1 + p1 * x2_ + s3,
                                                             r + 21 + (tid >> 2));
            __builtin_nontemporal_store(p4 + p3 * u1 + p2 * v2 + p1 * x3_ + s4,
                                        r + 85 + tid);  // coalesced
        }
    }
}

extern "C" void kernel_launch(void* const* d_in, const int* in_sizes, int n_in,
                              void* d_out, int out_size, void* d_ws, size_t ws_size,
                              hipStream_t stream) {
    const float* x = (const float*)d_in[0];   // (32, 512, 4) f32
    float* out = (float*)d_out;               // (32, 512, 341) f32
    float* Lsig = (float*)d_ws;               // 1024 * 344 floats (~1.4 MB)

    sigA<<<SIG_B * SIG_C, 256, 0, stream>>>(x, Lsig);
    sigC<<<SIG_B * SIG_C, 256, 0, stream>>>(x, Lsig, out);
}